// Round 7
// baseline (3744.967 us; speedup 1.0000x reference)
//
#include <hip/hip_runtime.h>
#include <cstdint>
#include <cstddef>

// Problem constants
#define kSEQ 100
#define kB   200
#define kNP  512
#define kNG  4096
#define kMP  256     // padded M for recurrent/encoder GEMMs

typedef _Float16 f16_t;
typedef f16_t f16x8 __attribute__((ext_vector_type(8)));
typedef float f32x4 __attribute__((ext_vector_type(4)));

// ---------------------------------------------------------------------------
// Pack fp32 row-major [srcM x srcK] into MFMA fragment order fp16:
// frag fid = m16*KB + kb; lane l, elem j  <-  src[m16*16+(l&15)][kb*32+(l>>4)*8+j]
// OOB rows zero-filled.  4 fragments per 256-thread block.
// ---------------------------------------------------------------------------
__global__ __launch_bounds__(256)
void k_pack(const float* __restrict__ src, f16_t* __restrict__ dst,
            int KB, int srcM, int srcK, int nFrag) {
    const int fid = blockIdx.x * 4 + (threadIdx.x >> 6);
    if (fid >= nFrag) return;
    const int lane = threadIdx.x & 63;
    const int m16  = fid / KB;
    const int kb   = fid - m16 * KB;
    const int row  = m16 * 16 + (lane & 15);
    const int kcol = kb * 32 + (lane >> 4) * 8;
    f16x8 h = {};
    if (row < srcM) {
        const float4* s = (const float4*)(src + (size_t)row * srcK + kcol);
        float4 v0 = s[0], v1 = s[1];
        h[0] = (f16_t)v0.x; h[1] = (f16_t)v0.y; h[2] = (f16_t)v0.z; h[3] = (f16_t)v0.w;
        h[4] = (f16_t)v1.x; h[5] = (f16_t)v1.y; h[6] = (f16_t)v1.z; h[7] = (f16_t)v1.w;
    }
    *(f16x8*)(dst + (size_t)fid * 512 + (size_t)lane * 8) = h;
}

// ---------------------------------------------------------------------------
// Convert fp32 -> fp16 row-major (for W_dec).  n8 = groups of 8 floats.
// ---------------------------------------------------------------------------
__global__ __launch_bounds__(256)
void k_half(const float* __restrict__ src, f16_t* __restrict__ dst, int n8) {
    int i = blockIdx.x * 256 + threadIdx.x;
    if (i >= n8) return;
    const float4* s = (const float4*)src + (size_t)i * 2;
    float4 v0 = s[0], v1 = s[1];
    f16x8 h;
    h[0] = (f16_t)v0.x; h[1] = (f16_t)v0.y; h[2] = (f16_t)v0.z; h[3] = (f16_t)v0.w;
    h[4] = (f16_t)v1.x; h[5] = (f16_t)v1.y; h[6] = (f16_t)v1.z; h[7] = (f16_t)v1.w;
    *(f16x8*)(dst + (size_t)i * 8) = h;
}

// ---------------------------------------------------------------------------
// Fused full-K RNN step (also encoder, mode 0).  NO split-K partial, NO
// separate reduce kernel.  Grid 256 blocks x 512 thr (8 waves).
// Block = 64x64 output tile, K = KB*32 (full).  Wave (ks,nh): k-slice ks of 4,
// n-half nh of 2 -> per-wave 64x32 tile over K/4; one LDS reduce at the end.
// XCD-colocated decode: n-tiles 8x64 cols per XCD -> whh slice (4.2 MB)
// stays resident in that XCD's L2 across all 100 steps.
// Epilogue: + velocity*W_ih^T, ReLU, write g fp32 / gb row-major fp16 /
// h packed fp16 (fragment order for the next step's A).
// ---------------------------------------------------------------------------
__global__ __launch_bounds__(512, 2)
void k_fstep(const f16_t* __restrict__ A, const f16_t* __restrict__ B, int KB,
             const float* __restrict__ velocity, const float* __restrict__ W_ih,
             float* __restrict__ gout, f16_t* __restrict__ gb,
             f16_t* __restrict__ hout, int t, int mode) {
    __shared__ float sred[4][64][68];   // 68-pad: +4 banks/row, conflict-light

    const int bid    = blockIdx.x;      // 0..255
    const int xcd    = bid & 7;
    const int idx    = bid >> 3;        // 0..31
    const int n_tile = xcd * 8 + (idx & 7);   // 0..63
    const int m_tile = idx >> 3;              // 0..3
    const int m0 = m_tile * 64;
    const int n0 = n_tile * 64;

    const int tid  = threadIdx.x;
    const int lane = tid & 63;
    const int wid  = tid >> 6;
    const int ks   = wid >> 1;   // k-slice 0..3
    const int nh   = wid & 1;    // n-half 0..1

    const int kPer = KB >> 2;
    const int kb0  = ks * kPer;

    f32x4 acc[4][2];
#pragma unroll
    for (int i = 0; i < 4; i++)
#pragma unroll
        for (int j = 0; j < 2; j++) acc[i][j] = (f32x4){0.f, 0.f, 0.f, 0.f};

    size_t aBase[4], bBase[2];
#pragma unroll
    for (int fm = 0; fm < 4; fm++)
        aBase[fm] = ((size_t)((m0 >> 4) + fm) * KB + kb0) * 512 + (size_t)lane * 8;
#pragma unroll
    for (int fn = 0; fn < 2; fn++)
        bBase[fn] = ((size_t)((n0 >> 4) + nh * 2 + fn) * KB + kb0) * 512 + (size_t)lane * 8;

#pragma unroll 2
    for (int kb = 0; kb < kPer; ++kb) {
        const size_t ko = (size_t)kb * 512;
        f16x8 a[4], b[2];
#pragma unroll
        for (int fm = 0; fm < 4; fm++) a[fm] = *(const f16x8*)(A + aBase[fm] + ko);
#pragma unroll
        for (int fn = 0; fn < 2; fn++) b[fn] = *(const f16x8*)(B + bBase[fn] + ko);
#pragma unroll
        for (int fm = 0; fm < 4; fm++)
#pragma unroll
            for (int fn = 0; fn < 2; fn++)
                acc[fm][fn] = __builtin_amdgcn_mfma_f32_16x16x32_f16(a[fm], b[fn], acc[fm][fn], 0, 0, 0);
    }

    // per-wave acc -> LDS k-slice
#pragma unroll
    for (int fm = 0; fm < 4; fm++)
#pragma unroll
        for (int fn = 0; fn < 2; fn++) {
            const int rb  = fm * 16 + ((lane >> 4) << 2);
            const int col = nh * 32 + fn * 16 + (lane & 15);
#pragma unroll
            for (int j = 0; j < 4; j++)
                sred[ks][rb + j][col] = acc[fm][fn][j];
        }
    __syncthreads();

    // ---- epilogue: 8 g's per thread (one f16x8) ----
    const int m16l = tid >> 7;          // 0..3
    const int r    = tid & 127;
    const int g0   = (r & 7) * 8;       // 0..56 (consecutive tids -> consecutive g)
    const int b15  = r >> 3;            // 0..15
    const int bl   = m16l * 16 + b15;   // 0..63
    const int brow = m0 + bl;
    const int gcol = n0 + g0;

    float v[8];
    {
        const float* s0 = &sred[0][bl][g0];
        const float* s1 = &sred[1][bl][g0];
        const float* s2 = &sred[2][bl][g0];
        const float* s3 = &sred[3][bl][g0];
#pragma unroll
        for (int e = 0; e < 8; e++) v[e] = s0[e] + s1[e] + s2[e] + s3[e];
    }

    if (mode == 1 && brow < kB) {
        const float2 vel = *(const float2*)(velocity + ((size_t)t * kB + brow) * 2);
        const float4* w = (const float4*)(W_ih + (size_t)gcol * 2);  // 4x float4 = 8 g's
#pragma unroll
        for (int i = 0; i < 4; i++) {
            float4 q = w[i];
            v[2 * i]     = fmaxf(0.f, v[2 * i]     + vel.x * q.x + vel.y * q.y);
            v[2 * i + 1] = fmaxf(0.f, v[2 * i + 1] + vel.x * q.z + vel.y * q.w);
        }
        float4 o0 = {v[0], v[1], v[2], v[3]};
        float4 o1 = {v[4], v[5], v[6], v[7]};
        float4* gp = (float4*)(gout + ((size_t)t * kB + brow) * kNG + gcol);
        gp[0] = o0; gp[1] = o1;
    }

    f16x8 h8;
#pragma unroll
    for (int e = 0; e < 8; e++) h8[e] = (f16_t)v[e];

    if (mode == 1 && gb && brow < kB)
        *(f16x8*)(gb + ((size_t)t * kB + brow) * kNG + gcol) = h8;

    // packed h for next step's A operand: frag = (brow/16)*128 + gcol/32
    {
        const int lane_pk = ((gcol >> 3) & 3) * 16 + (brow & 15);
        const size_t off = ((size_t)((brow >> 4) * (kNG / 32) + (gcol >> 5)) * 64 + lane_pk) * 8;
        *(f16x8*)(hout + off) = h8;
    }
}

// ---------------------------------------------------------------------------
// Decoder (round-5 proven form): logits[r][p] = sum_g G[r][g] * Wdec[p][g].
// LDS-staged with XOR swizzle; Gb (fp16) if non-null else Gf converted.
// Flat grid 632, XCD-colocated (4 n-tiles of an m-panel per XCD).
// ---------------------------------------------------------------------------
__global__ __launch_bounds__(256)
void k_dec(const float* __restrict__ Gf, const f16_t* __restrict__ Gb,
           const f16_t* __restrict__ Wd, float* __restrict__ out) {
    __shared__ __align__(16) f16_t sA[128 * 64];
    __shared__ __align__(16) f16_t sB[128 * 64];

    const int bid  = blockIdx.x;        // 0..631
    const int xcd  = bid & 7;
    const int idx  = bid >> 3;          // 0..78
    const int tile = xcd * 79 + idx;    // tile = m_t*4 + n_t
    if (tile >= 157 * 4) return;
    const int m0 = (tile >> 2) * 128;
    const int n0 = (tile & 3) * 128;

    const int tid  = threadIdx.x;
    const int lane = tid & 63;
    const int wid  = tid >> 6;
    const int wr   = wid >> 1;
    const int wc   = wid & 1;
    const int M    = kSEQ * kB;   // 20000

    f32x4 acc[4][4];
#pragma unroll
    for (int i = 0; i < 4; i++)
#pragma unroll
        for (int j = 0; j < 4; j++) acc[i][j] = (f32x4){0.f, 0.f, 0.f, 0.f};

    const int sr   = tid >> 1;
    const int half = tid & 1;
    const int sc   = half * 32;
    const unsigned int swzrow = ((unsigned)sr & 7u) << 4;
    const unsigned int sbase  = (unsigned)sr * 128u + (unsigned)half * 64u;
    int arow = m0 + sr; if (arow > M - 1) arow = M - 1;

    for (int k0 = 0; k0 < kNG; k0 += 64) {
        __syncthreads();
        if (Gb) {
            const uint4* gA = (const uint4*)(Gb + (size_t)arow * kNG + k0 + sc);
#pragma unroll
            for (int i = 0; i < 4; i++) {
                unsigned int off = (sbase + (unsigned)i * 16u) ^ swzrow;
                *(uint4*)((char*)sA + off) = gA[i];
            }
        } else {
            const float4* gA = (const float4*)(Gf + (size_t)arow * kNG + k0 + sc);
#pragma unroll
            for (int i = 0; i < 4; i++) {
                float4 a0 = gA[2 * i], a1 = gA[2 * i + 1];
                f16x8 u;
                u[0] = (f16_t)a0.x; u[1] = (f16_t)a0.y; u[2] = (f16_t)a0.z; u[3] = (f16_t)a0.w;
                u[4] = (f16_t)a1.x; u[5] = (f16_t)a1.y; u[6] = (f16_t)a1.z; u[7] = (f16_t)a1.w;
                unsigned int off = (sbase + (unsigned)i * 16u) ^ swzrow;
                *(f16x8*)((char*)sA + off) = u;
            }
        }
        {
            const uint4* gB = (const uint4*)(Wd + (size_t)(n0 + sr) * kNG + k0 + sc);
#pragma unroll
            for (int i = 0; i < 4; i++) {
                unsigned int off = (sbase + (unsigned)i * 16u) ^ swzrow;
                *(uint4*)((char*)sB + off) = gB[i];
            }
        }
        __syncthreads();
#pragma unroll
        for (int ks2 = 0; ks2 < 2; ks2++) {
            f16x8 a[4], b[4];
            const unsigned int klane = (unsigned)(lane >> 4) * 16u + (unsigned)ks2 * 64u;
#pragma unroll
            for (int fm = 0; fm < 4; fm++) {
                const unsigned int row = (unsigned)(wr * 64 + fm * 16 + (lane & 15));
                const unsigned int off = (row * 128u + klane) ^ ((row & 7u) << 4);
                a[fm] = *(const f16x8*)((const char*)sA + off);
            }
#pragma unroll
            for (int fn = 0; fn < 4; fn++) {
                const unsigned int row = (unsigned)(wc * 64 + fn * 16 + (lane & 15));
                const unsigned int off = (row * 128u + klane) ^ ((row & 7u) << 4);
                b[fn] = *(const f16x8*)((const char*)sB + off);
            }
#pragma unroll
            for (int fm = 0; fm < 4; fm++)
#pragma unroll
                for (int fn = 0; fn < 4; fn++)
                    acc[fm][fn] = __builtin_amdgcn_mfma_f32_16x16x32_f16(a[fm], b[fn], acc[fm][fn], 0, 0, 0);
        }
    }

#pragma unroll
    for (int fm = 0; fm < 4; fm++)
#pragma unroll
        for (int fn = 0; fn < 4; fn++) {
            const int row0 = m0 + wr * 64 + fm * 16 + ((lane >> 4) << 2);
            const int col  = n0 + wc * 64 + fn * 16 + (lane & 15);
#pragma unroll
            for (int j = 0; j < 4; j++) {
                const int row = row0 + j;
                if (row < M) out[(size_t)row * kNP + col] = acc[fm][fn][j];
            }
        }
}

// ---------------------------------------------------------------------------
extern "C" void kernel_launch(void* const* d_in, const int* in_sizes, int n_in,
                              void* d_out, int out_size, void* d_ws, size_t ws_size,
                              hipStream_t stream) {
    const float* velocity = (const float*)d_in[0];
    const float* init_pc  = (const float*)d_in[1];
    const float* W_enc    = (const float*)d_in[2];
    const float* W_ih     = (const float*)d_in[3];
    const float* W_hh     = (const float*)d_in[4];
    const float* W_dec    = (const float*)d_in[5];

    float* logits = (float*)d_out;                         // (100,200,512)
    float* gout   = logits + (size_t)kSEQ * kB * kNP;      // (100,200,4096)

    char* ws = (char*)d_ws;
    size_t off = 0;
    auto alloc = [&](size_t bytes) -> void* {
        void* p = ws + off;
        off += (bytes + 255) & ~(size_t)255;
        return p;
    };
    // fragment-packed operands ([M/16][K/32] fragments of 512 f16)
    f16_t* whh_pk  = (f16_t*)alloc((size_t)256 * 128 * 512 * 2);   // 33.5 MB
    f16_t* wenc_pk = (f16_t*)alloc((size_t)256 * 16 * 512 * 2);    //  4.2 MB
    f16_t* ip_pk   = (f16_t*)alloc((size_t)16 * 16 * 512 * 2);     //  0.26 MB
    f16_t* h_pk[2];
    h_pk[0] = (f16_t*)alloc((size_t)16 * 128 * 512 * 2);           //  2.1 MB
    h_pk[1] = (f16_t*)alloc((size_t)16 * 128 * 512 * 2);
    f16_t* wdec_h  = (f16_t*)alloc((size_t)kNP * kNG * 2);         //  4.2 MB row-major
    // row-major fp16 copy of g for the decoder (164 MB) — if ws allows
    f16_t* gb = nullptr;
    if (ws_size >= off + (size_t)kSEQ * kB * kNG * 2 + 4096)
        gb = (f16_t*)alloc((size_t)kSEQ * kB * kNG * 2);

    // --- pack weights / initial state ---
    int nf;
    nf = 256 * 128;  // W_hh (4096 x 4096)
    k_pack<<<(nf + 3) / 4, 256, 0, stream>>>(W_hh, whh_pk, 128, kNG, kNG, nf);
    nf = 256 * 16;   // W_enc (4096 x 512)
    k_pack<<<(nf + 3) / 4, 256, 0, stream>>>(W_enc, wenc_pk, 16, kNG, kNP, nf);
    nf = 16 * 16;    // init_pc (200 x 512 -> padded 256 rows)
    k_pack<<<(nf + 3) / 4, 256, 0, stream>>>(init_pc, ip_pk, 16, kB, kNP, nf);
    int n8 = kNP * kNG / 8;   // W_dec row-major fp16
    k_half<<<(n8 + 255) / 256, 256, 0, stream>>>(W_dec, wdec_h, n8);

    // --- encoder: h0 = init_pc @ W_enc^T (mode 0) ---
    k_fstep<<<256, 512, 0, stream>>>(ip_pk, wenc_pk, kNP / 32,
                                     velocity, W_ih, nullptr, nullptr,
                                     h_pk[0], 0, 0);

    // --- recurrent scan: one fused kernel per step ---
    int p = 0;
    for (int t = 0; t < kSEQ; t++) {
        k_fstep<<<256, 512, 0, stream>>>(h_pk[p], whh_pk, kNG / 32,
                                         velocity, W_ih, gout, gb,
                                         h_pk[p ^ 1], t, 1);
        p ^= 1;
    }

    // --- decoder ---
    k_dec<<<632, 256, 0, stream>>>(gout, gb, wdec_h, logits);
}

// Round 8
// 2442.896 us; speedup vs baseline: 1.5330x; 1.5330x over previous
//
#include <hip/hip_runtime.h>
#include <cstdint>
#include <cstddef>

// Problem constants
#define kSEQ 100
#define kB   200
#define kNP  512
#define kNG  4096
#define kMP  256     // padded M for recurrent/encoder GEMMs
#define KSPLIT 8

typedef _Float16 f16_t;
typedef f16_t f16x8 __attribute__((ext_vector_type(8)));
typedef f16_t f16x4 __attribute__((ext_vector_type(4)));
typedef float f32x4 __attribute__((ext_vector_type(4)));

// ---------------------------------------------------------------------------
// Convert fp32 -> fp16 (RTN).  n8 = number of 8-float groups.
// ---------------------------------------------------------------------------
__global__ __launch_bounds__(256)
void k_half(const float* __restrict__ src, f16_t* __restrict__ dst, int n8) {
    int i = blockIdx.x * 256 + threadIdx.x;
    if (i >= n8) return;
    const float4* s = (const float4*)src + (size_t)i * 2;
    float4 v0 = s[0], v1 = s[1];
    f16x8 h;
    h[0] = (f16_t)v0.x; h[1] = (f16_t)v0.y; h[2] = (f16_t)v0.z; h[3] = (f16_t)v0.w;
    h[4] = (f16_t)v1.x; h[5] = (f16_t)v1.y; h[6] = (f16_t)v1.z; h[7] = (f16_t)v1.w;
    *(f16x8*)(dst + (size_t)i * 8) = h;
}

// ---------------------------------------------------------------------------
// Single-product fp16 MFMA GEMM (r5 proven structure: LDS staging with XOR
// swizzle, 128x128 tile, 4 waves of 64x64).  CHANGE vs r5: partials are
// written fp16 and only for the kB=200 real rows -> split-K roundtrip
// 67 MB -> 26 MB per step.
// Grid: (N/128, kMP/128, KSPLIT) = 512 blocks -> 2 blocks/CU.
// ---------------------------------------------------------------------------
__global__ __launch_bounds__(256)
void k_gemm_f16(const f16_t* __restrict__ A, int lda,
                const f16_t* __restrict__ B, int ldb,
                f16_t* __restrict__ part, int kPerChunk) {
    __shared__ __align__(16) f16_t sA[128 * 64];
    __shared__ __align__(16) f16_t sB[128 * 64];

    const int tid  = threadIdx.x;
    const int lane = tid & 63;
    const int wid  = tid >> 6;
    const int wr   = wid >> 1;   // wave row (0..1)
    const int wc   = wid & 1;    // wave col (0..1)
    const int m0   = blockIdx.y * 128;
    const int n0   = blockIdx.x * 128;
    const int kBase = blockIdx.z * kPerChunk;

    f32x4 acc[4][4];
#pragma unroll
    for (int i = 0; i < 4; i++)
#pragma unroll
        for (int j = 0; j < 4; j++) acc[i][j] = (f32x4){0.f, 0.f, 0.f, 0.f};

    const int sr = tid >> 1;          // staging row 0..127
    const int sc = (tid & 1) * 32;    // staging col offset (f16 elems)
    const unsigned int swzrow = ((unsigned)sr & 7u) << 4;
    const unsigned int sbase  = (unsigned)sr * 128u + (unsigned)(tid & 1) * 64u;

    for (int kb = 0; kb < kPerChunk; kb += 64) {
        const int k0 = kBase + kb;
        __syncthreads();
        {
            const uint4* gA = (const uint4*)(A + (size_t)(m0 + sr) * (size_t)lda + k0 + sc);
            const uint4* gB = (const uint4*)(B + (size_t)(n0 + sr) * (size_t)ldb + k0 + sc);
#pragma unroll
            for (int i = 0; i < 4; i++) {
                unsigned int off = (sbase + (unsigned)i * 16u) ^ swzrow;
                *(uint4*)((char*)sA + off) = gA[i];
                *(uint4*)((char*)sB + off) = gB[i];
            }
        }
        __syncthreads();
#pragma unroll
        for (int ks2 = 0; ks2 < 2; ks2++) {
            f16x8 a[4], b[4];
            const unsigned int klane = (unsigned)(lane >> 4) * 16u + (unsigned)ks2 * 64u;
#pragma unroll
            for (int fm = 0; fm < 4; fm++) {
                const unsigned int row = (unsigned)(wr * 64 + fm * 16 + (lane & 15));
                const unsigned int off = (row * 128u + klane) ^ ((row & 7u) << 4);
                a[fm] = *(const f16x8*)((const char*)sA + off);
            }
#pragma unroll
            for (int fn = 0; fn < 4; fn++) {
                const unsigned int row = (unsigned)(wc * 64 + fn * 16 + (lane & 15));
                const unsigned int off = (row * 128u + klane) ^ ((row & 7u) << 4);
                b[fn] = *(const f16x8*)((const char*)sB + off);
            }
#pragma unroll
            for (int fm = 0; fm < 4; fm++)
#pragma unroll
                for (int fn = 0; fn < 4; fn++)
                    acc[fm][fn] = __builtin_amdgcn_mfma_f32_16x16x32_f16(a[fm], b[fn], acc[fm][fn], 0, 0, 0);
        }
    }

    // fp16 partial, 200-row pitch, rows >= kB skipped
    f16_t* po = part + (size_t)blockIdx.z * ((size_t)kB * kNG);
#pragma unroll
    for (int fm = 0; fm < 4; fm++)
#pragma unroll
        for (int fn = 0; fn < 4; fn++) {
            const int row0 = m0 + wr * 64 + fm * 16 + ((lane >> 4) << 2);
            const int col  = n0 + wc * 64 + fn * 16 + (lane & 15);
#pragma unroll
            for (int j = 0; j < 4; j++) {
                const int row = row0 + j;
                if (row < kB)
                    po[(size_t)row * kNG + col] = (f16_t)acc[fm][fn][j];
            }
        }
}

// ---------------------------------------------------------------------------
// Reduce KSPLIT fp16 K-partials; mode 1: add velocity*W_ih^T, ReLU, store g
// (fp32 output) + fp16 copies for decoder (gb) and next step (hout).
// Grid: (4, kB), 256 threads, 4 g's per thread.
// ---------------------------------------------------------------------------
__global__ __launch_bounds__(256)
void k_reduce(const f16_t* __restrict__ part,
              const float* __restrict__ velocity, const float* __restrict__ W_ih,
              float* __restrict__ gout, f16_t* __restrict__ gb,
              f16_t* __restrict__ hout, int t, int mode) {
    const int b = blockIdx.y;
    const int g = blockIdx.x * 1024 + threadIdx.x * 4;

    float v0 = 0.f, v1 = 0.f, v2 = 0.f, v3 = 0.f;
#pragma unroll
    for (int ks = 0; ks < KSPLIT; ks++) {
        f16x4 p = *(const f16x4*)(part + (size_t)ks * ((size_t)kB * kNG) + (size_t)b * kNG + g);
        v0 += (float)p[0]; v1 += (float)p[1]; v2 += (float)p[2]; v3 += (float)p[3];
    }
    if (mode == 1) {
        const float2 vel = *(const float2*)(velocity + ((size_t)t * kB + b) * 2);
        const float4 w01 = *(const float4*)(W_ih + (size_t)g * 2);
        const float4 w23 = *(const float4*)(W_ih + (size_t)g * 2 + 4);
        v0 = fmaxf(0.f, v0 + vel.x * w01.x + vel.y * w01.y);
        v1 = fmaxf(0.f, v1 + vel.x * w01.z + vel.y * w01.w);
        v2 = fmaxf(0.f, v2 + vel.x * w23.x + vel.y * w23.y);
        v3 = fmaxf(0.f, v3 + vel.x * w23.z + vel.y * w23.w);
        float4 o; o.x = v0; o.y = v1; o.z = v2; o.w = v3;
        *(float4*)(gout + ((size_t)t * kB + b) * kNG + g) = o;
    }
    f16x4 h;
    h[0] = (f16_t)v0; h[1] = (f16_t)v1; h[2] = (f16_t)v2; h[3] = (f16_t)v3;
    *(f16x4*)(hout + (size_t)b * kNG + g) = h;
    if (mode == 1 && gb)
        *(f16x4*)(gb + ((size_t)t * kB + b) * kNG + g) = h;
}

// ---------------------------------------------------------------------------
// Decoder (r5 proven form): logits[r][p] = sum_g G[r][g] * Wdec[p][g].
// LDS-staged with XOR swizzle; Gb (fp16 G) if non-null else Gf converted.
// Flat grid 632, XCD-colocated (4 n-tiles of an m-panel per XCD).
// ---------------------------------------------------------------------------
__global__ __launch_bounds__(256)
void k_dec(const float* __restrict__ Gf, const f16_t* __restrict__ Gb,
           const f16_t* __restrict__ Wd, float* __restrict__ out) {
    __shared__ __align__(16) f16_t sA[128 * 64];
    __shared__ __align__(16) f16_t sB[128 * 64];

    const int bid  = blockIdx.x;        // 0..631
    const int xcd  = bid & 7;
    const int idx  = bid >> 3;          // 0..78
    const int tile = xcd * 79 + idx;    // tile = m_t*4 + n_t
    if (tile >= 157 * 4) return;
    const int m0 = (tile >> 2) * 128;
    const int n0 = (tile & 3) * 128;

    const int tid  = threadIdx.x;
    const int lane = tid & 63;
    const int wid  = tid >> 6;
    const int wr   = wid >> 1;
    const int wc   = wid & 1;
    const int M    = kSEQ * kB;   // 20000

    f32x4 acc[4][4];
#pragma unroll
    for (int i = 0; i < 4; i++)
#pragma unroll
        for (int j = 0; j < 4; j++) acc[i][j] = (f32x4){0.f, 0.f, 0.f, 0.f};

    const int sr   = tid >> 1;
    const int half = tid & 1;
    const int sc   = half * 32;
    const unsigned int swzrow = ((unsigned)sr & 7u) << 4;
    const unsigned int sbase  = (unsigned)sr * 128u + (unsigned)half * 64u;
    int arow = m0 + sr; if (arow > M - 1) arow = M - 1;

    for (int k0 = 0; k0 < kNG; k0 += 64) {
        __syncthreads();
        if (Gb) {
            const uint4* gA = (const uint4*)(Gb + (size_t)arow * kNG + k0 + sc);
#pragma unroll
            for (int i = 0; i < 4; i++) {
                unsigned int off = (sbase + (unsigned)i * 16u) ^ swzrow;
                *(uint4*)((char*)sA + off) = gA[i];
            }
        } else {
            const float4* gA = (const float4*)(Gf + (size_t)arow * kNG + k0 + sc);
#pragma unroll
            for (int i = 0; i < 4; i++) {
                float4 a0 = gA[2 * i], a1 = gA[2 * i + 1];
                f16x8 u;
                u[0] = (f16_t)a0.x; u[1] = (f16_t)a0.y; u[2] = (f16_t)a0.z; u[3] = (f16_t)a0.w;
                u[4] = (f16_t)a1.x; u[5] = (f16_t)a1.y; u[6] = (f16_t)a1.z; u[7] = (f16_t)a1.w;
                unsigned int off = (sbase + (unsigned)i * 16u) ^ swzrow;
                *(f16x8*)((char*)sA + off) = u;
            }
        }
        {
            const uint4* gB = (const uint4*)(Wd + (size_t)(n0 + sr) * kNG + k0 + sc);
#pragma unroll
            for (int i = 0; i < 4; i++) {
                unsigned int off = (sbase + (unsigned)i * 16u) ^ swzrow;
                *(uint4*)((char*)sB + off) = gB[i];
            }
        }
        __syncthreads();
#pragma unroll
        for (int ks2 = 0; ks2 < 2; ks2++) {
            f16x8 a[4], b[4];
            const unsigned int klane = (unsigned)(lane >> 4) * 16u + (unsigned)ks2 * 64u;
#pragma unroll
            for (int fm = 0; fm < 4; fm++) {
                const unsigned int row = (unsigned)(wr * 64 + fm * 16 + (lane & 15));
                const unsigned int off = (row * 128u + klane) ^ ((row & 7u) << 4);
                a[fm] = *(const f16x8*)((const char*)sA + off);
            }
#pragma unroll
            for (int fn = 0; fn < 4; fn++) {
                const unsigned int row = (unsigned)(wc * 64 + fn * 16 + (lane & 15));
                const unsigned int off = (row * 128u + klane) ^ ((row & 7u) << 4);
                b[fn] = *(const f16x8*)((const char*)sB + off);
            }
#pragma unroll
            for (int fm = 0; fm < 4; fm++)
#pragma unroll
                for (int fn = 0; fn < 4; fn++)
                    acc[fm][fn] = __builtin_amdgcn_mfma_f32_16x16x32_f16(a[fm], b[fn], acc[fm][fn], 0, 0, 0);
        }
    }

#pragma unroll
    for (int fm = 0; fm < 4; fm++)
#pragma unroll
        for (int fn = 0; fn < 4; fn++) {
            const int row0 = m0 + wr * 64 + fm * 16 + ((lane >> 4) << 2);
            const int col  = n0 + wc * 64 + fn * 16 + (lane & 15);
#pragma unroll
            for (int j = 0; j < 4; j++) {
                const int row = row0 + j;
                if (row < M) out[(size_t)row * kNP + col] = acc[fm][fn][j];
            }
        }
}

// ---------------------------------------------------------------------------
extern "C" void kernel_launch(void* const* d_in, const int* in_sizes, int n_in,
                              void* d_out, int out_size, void* d_ws, size_t ws_size,
                              hipStream_t stream) {
    const float* velocity = (const float*)d_in[0];
    const float* init_pc  = (const float*)d_in[1];
    const float* W_enc    = (const float*)d_in[2];
    const float* W_ih     = (const float*)d_in[3];
    const float* W_hh     = (const float*)d_in[4];
    const float* W_dec    = (const float*)d_in[5];

    float* logits = (float*)d_out;                         // (100,200,512)
    float* gout   = logits + (size_t)kSEQ * kB * kNP;      // (100,200,4096)

    char* ws = (char*)d_ws;
    size_t off = 0;
    auto alloc = [&](size_t bytes) -> void* {
        void* p = ws + off;
        off += (bytes + 255) & ~(size_t)255;
        return p;
    };
    f16_t* whh  = (f16_t*)alloc((size_t)kNG * kNG * 2);
    f16_t* wdec = (f16_t*)alloc((size_t)kNP * kNG * 2);
    f16_t* wenc = (f16_t*)alloc((size_t)kNG * kNP * 2);
    f16_t* ip   = (f16_t*)alloc((size_t)kMP * kNP * 2);
    f16_t* h_buf[2];
    h_buf[0] = (f16_t*)alloc((size_t)kMP * kNG * 2);
    h_buf[1] = (f16_t*)alloc((size_t)kMP * kNG * 2);
    f16_t* partial = (f16_t*)alloc((size_t)KSPLIT * kB * kNG * 2);  // 13.1 MB fp16
    // fp16 copy of g for the decoder (164 MB) — only if ws allows
    f16_t* gb = nullptr;
    if (ws_size >= off + (size_t)kSEQ * kB * kNG * 2 + 4096)
        gb = (f16_t*)alloc((size_t)kSEQ * kB * kNG * 2);

    // zero init_pc pad rows (their partial rows are skipped, but keep clean)
    hipMemsetAsync(ip + (size_t)kB * kNP, 0, (size_t)(kMP - kB) * kNP * 2, stream);

    // --- fp32 -> fp16 conversions ---
    int n8;
    n8 = kNG * kNG / 8;
    k_half<<<(n8 + 255) / 256, 256, 0, stream>>>(W_hh, whh, n8);
    n8 = kNP * kNG / 8;
    k_half<<<(n8 + 255) / 256, 256, 0, stream>>>(W_dec, wdec, n8);
    n8 = kNG * kNP / 8;
    k_half<<<(n8 + 255) / 256, 256, 0, stream>>>(W_enc, wenc, n8);
    n8 = kB * kNP / 8;
    k_half<<<(n8 + 255) / 256, 256, 0, stream>>>(init_pc, ip, n8);

    dim3 gG(kNG / 128, kMP / 128, KSPLIT);   // (32, 2, 8) = 512 blocks
    dim3 gR(4, kB);

    // --- encoder: h0 = init_pc @ W_enc^T ---
    k_gemm_f16<<<gG, 256, 0, stream>>>(ip, kNP, wenc, kNP, partial, kNP / KSPLIT);
    k_reduce<<<gR, 256, 0, stream>>>(partial, velocity, W_ih, nullptr, nullptr, h_buf[0], 0, 0);

    // --- recurrent scan ---
    int p = 0;
    for (int t = 0; t < kSEQ; t++) {
        k_gemm_f16<<<gG, 256, 0, stream>>>(h_buf[p], kNG, whh, kNG, partial, kNG / KSPLIT);
        k_reduce<<<gR, 256, 0, stream>>>(partial, velocity, W_ih, gout, gb, h_buf[p ^ 1], t, 1);
        p ^= 1;
    }

    // --- decoder ---
    k_dec<<<632, 256, 0, stream>>>(gout, gb, wdec, logits);
}